// Round 4
// baseline (304.298 us; speedup 1.0000x reference)
//
#include <hip/hip_runtime.h>
#include <hip/hip_bf16.h>

typedef __attribute__((ext_vector_type(4))) float floatx4;
typedef __attribute__((ext_vector_type(8))) short short8;
typedef __attribute__((ext_vector_type(8))) unsigned short ushortx8;

#define K1 2048
#define N1 1024

__device__ __forceinline__ unsigned short f2bf(float f) {
  __hip_bfloat16 h = __float2bfloat16(f);
  return __builtin_bit_cast(unsigned short, h);
}

__device__ __forceinline__ void gload_lds16(const void* g, void* l) {
  __builtin_amdgcn_global_load_lds(
      (__attribute__((address_space(1))) void*)const_cast<void*>(g),
      (__attribute__((address_space(3))) void*)l, 16, 0, 0);
}

__global__ void cvt_bf16_kernel(const float* __restrict__ src,
                                unsigned short* __restrict__ dst, int n4) {
  int i = blockIdx.x * blockDim.x + threadIdx.x;
  if (i >= n4) return;
  float4 f = reinterpret_cast<const float4*>(src)[i];
  ushort4 o;
  o.x = f2bf(f.x); o.y = f2bf(f.y); o.z = f2bf(f.z); o.w = f2bf(f.w);
  reinterpret_cast<ushort4*>(dst)[i] = o;
}

// Gather + fp32->bf16: xb[row][k] = bf16(tok[idxs[row]][k]). One block per row.
__global__ __launch_bounds__(256) void gather_cvt_kernel(
    const int* __restrict__ idxs, const float* __restrict__ tok,
    unsigned short* __restrict__ xb) {
  const int row = blockIdx.x;
  const float* src = tok + (size_t)idxs[row] * K1;
  unsigned short* dst = xb + (size_t)row * K1;
  const int o = threadIdx.x * 8;
  const float4 f0 = *reinterpret_cast<const float4*>(src + o);
  const float4 f1 = *reinterpret_cast<const float4*>(src + o + 4);
  ushortx8 u;
  u[0] = f2bf(f0.x); u[1] = f2bf(f0.y); u[2] = f2bf(f0.z); u[3] = f2bf(f0.w);
  u[4] = f2bf(f1.x); u[5] = f2bf(f1.y); u[6] = f2bf(f1.z); u[7] = f2bf(f1.w);
  *reinterpret_cast<ushortx8*>(dst + o) = u;
}

// 256x256-tile GEMM, BK=64, 8 waves, counted-vmcnt double buffer.
// C[m][n] = sum_k A[m][k] * Bw[n][k] (+bias). EPI 0: GELU->bf16; EPI 1: fp32.
// LDS per op per buf: [kg 0..7][row 0..255][8 bf16] = 16384 shorts (32 KB).
template <int KDIM, int EPI>
__global__ __launch_bounds__(512, 2) void gemm256_kernel(
    const unsigned short* __restrict__ A, const unsigned short* __restrict__ Bw,
    const float* __restrict__ bias, void* __restrict__ outp) {
  __shared__ unsigned short Asub[2][16384];
  __shared__ unsigned short Bsub[2][16384];
  const int t = threadIdx.x;
  const int p = blockIdx.x;
  const int bid = (p & 7) * 32 + (p >> 3);  // XCD x owns contiguous bm range
  const int bm = bid >> 2, bn = bid & 3;
  const int brow0 = bm * 256, bcol0 = bn * 256;
  const int lane = t & 63, w = t >> 6;
  const int wm = w >> 2, wn = w & 3;         // wave grid 2M x 4N, per-wave C 128x64
  const int fr = lane & 15, kg2 = lane >> 4;

  // staging: thread t covers rows (t&255), kg = (t>>8)+2q, q=0..3 (16B chunks)
  const unsigned short* asrc = A + (size_t)(brow0 + (t & 255)) * KDIM + (t >> 8) * 8;
  const unsigned short* bsrc = Bw + (size_t)(bcol0 + (t & 255)) * KDIM + (t >> 8) * 8;

  // fragment read bases (shorts): block kg = ks*4+kg2 holds k = ks*32+kg2*8 ..+8
  const int abase = kg2 * 2048 + wm * 1024 + fr * 8;
  const int bbase = kg2 * 2048 + wn * 512 + fr * 8;

  floatx4 acc[8][4] = {};
  constexpr int NT = KDIM / 64;

  auto stage = [&](int d, int k0) {
#pragma unroll
    for (int q = 0; q < 4; ++q) {
      gload_lds16(asrc + k0 + q * 16, &Asub[d][t * 8 + q * 4096]);
      gload_lds16(bsrc + k0 + q * 16, &Bsub[d][t * 8 + q * 4096]);
    }
  };
  auto compute = [&](int cur) {
#pragma unroll
    for (int ks = 0; ks < 2; ++ks) {
      short8 bf[4];
#pragma unroll
      for (int j = 0; j < 4; ++j)
        bf[j] = *reinterpret_cast<const short8*>(&Bsub[cur][ks * 8192 + bbase + j * 128]);
#pragma unroll
      for (int i = 0; i < 8; ++i) {
        const short8 af = *reinterpret_cast<const short8*>(&Asub[cur][ks * 8192 + abase + i * 128]);
#pragma unroll
        for (int j = 0; j < 4; ++j)
          acc[i][j] = __builtin_amdgcn_mfma_f32_16x16x32_bf16(af, bf[j], acc[i][j], 0, 0, 0);
      }
    }
  };

  stage(0, 0);
#pragma unroll 1
  for (int it = 0; it < NT - 1; ++it) {
    const int cur = it & 1;
    stage(cur ^ 1, (it + 1) * 64);
    // own 8 loads for tile `cur` (issued last iter/prologue) landed; the 8
    // just-issued stay in flight across the barrier and the MFMA phase.
    asm volatile("s_waitcnt vmcnt(8)\ns_barrier" ::: "memory");
    compute(cur);
    // all my LDS reads done -> after barrier everyone may overwrite this buf
    asm volatile("s_waitcnt lgkmcnt(0)\ns_barrier" ::: "memory");
  }
  asm volatile("s_waitcnt vmcnt(0)\ns_barrier" ::: "memory");
  compute((NT - 1) & 1);

  // epilogue: C/D map col=lane&15, row=(lane>>4)*4+r (m89-verified convention)
  const int er0 = brow0 + wm * 128 + kg2 * 4;
  const int ec0 = bcol0 + wn * 64 + fr;
  if constexpr (EPI == 0) {
    unsigned short* hout = (unsigned short*)outp;
#pragma unroll
    for (int j = 0; j < 4; ++j) {
      const float bv = bias[ec0 + j * 16];
#pragma unroll
      for (int i = 0; i < 8; ++i)
#pragma unroll
        for (int r = 0; r < 4; ++r) {
          float v = acc[i][j][r] + bv;
          v = 0.5f * v * (1.0f + erff(v * 0.70710678118654752f));
          hout[(size_t)(er0 + i * 16 + r) * N1 + (ec0 + j * 16)] = f2bf(v);
        }
    }
  } else {
    float* fout = (float*)outp;
#pragma unroll
    for (int j = 0; j < 4; ++j) {
      const float bv = bias[ec0 + j * 16];
#pragma unroll
      for (int i = 0; i < 8; ++i)
#pragma unroll
        for (int r = 0; r < 4; ++r)
          fout[(size_t)(er0 + i * 16 + r) * N1 + (ec0 + j * 16)] = acc[i][j][r] + bv;
    }
  }
}

extern "C" void kernel_launch(void* const* d_in, const int* in_sizes, int n_in,
                              void* d_out, int out_size, void* d_ws, size_t ws_size,
                              hipStream_t stream) {
  const int* idxs = (const int*)d_in[0];
  const float* tok = (const float*)d_in[1];
  const float* W1 = (const float*)d_in[2];
  const float* b1 = (const float*)d_in[3];
  const float* W2 = (const float*)d_in[4];
  const float* b2 = (const float*)d_in[5];
  float* out = (float*)d_out;

  unsigned short* W1b = (unsigned short*)d_ws;                          // 4 MB
  unsigned short* W2b = (unsigned short*)((char*)d_ws + (4u << 20));    // 2 MB
  unsigned short* xb = (unsigned short*)((char*)d_ws + (6u << 20));     // 64 MB
  unsigned short* hbuf = (unsigned short*)((char*)d_ws + (70u << 20));  // 32 MB

  cvt_bf16_kernel<<<2048, 256, 0, stream>>>(W1, W1b, 524288);
  cvt_bf16_kernel<<<1024, 256, 0, stream>>>(W2, W2b, 262144);
  gather_cvt_kernel<<<16384, 256, 0, stream>>>(idxs, tok, xb);
  gemm256_kernel<2048, 0><<<256, 512, 0, stream>>>(xb, W1b, b1, hbuf);
  gemm256_kernel<1024, 1><<<256, 512, 0, stream>>>(hbuf, W2b, b2, out);
}

// Round 5
// 166.640 us; speedup vs baseline: 1.8261x; 1.8261x over previous
//
#include <hip/hip_runtime.h>
#include <hip/hip_bf16.h>

typedef __attribute__((ext_vector_type(4))) float floatx4;
typedef __attribute__((ext_vector_type(8))) short short8;
typedef __attribute__((ext_vector_type(8))) unsigned short ushortx8;

#define K1 2048
#define N1 1024

__device__ __forceinline__ unsigned short f2bf(float f) {
  __hip_bfloat16 h = __float2bfloat16(f);
  return __builtin_bit_cast(unsigned short, h);
}

__device__ __forceinline__ void gload_lds16(const void* g, void* l) {
  __builtin_amdgcn_global_load_lds(
      (__attribute__((address_space(1))) void*)const_cast<void*>(g),
      (__attribute__((address_space(3))) void*)l, 16, 0, 0);
}

__global__ void cvt_bf16_kernel(const float* __restrict__ src,
                                unsigned short* __restrict__ dst, int n4) {
  int i = blockIdx.x * blockDim.x + threadIdx.x;
  if (i >= n4) return;
  float4 f = reinterpret_cast<const float4*>(src)[i];
  ushort4 o;
  o.x = f2bf(f.x); o.y = f2bf(f.y); o.z = f2bf(f.z); o.w = f2bf(f.w);
  reinterpret_cast<ushort4*>(dst)[i] = o;
}

// Gather + fp32->bf16: xb[row][k] = bf16(tok[idxs[row]][k]). One block per row.
__global__ __launch_bounds__(256) void gather_cvt_kernel(
    const int* __restrict__ idxs, const float* __restrict__ tok,
    unsigned short* __restrict__ xb) {
  const int row = blockIdx.x;
  const float* src = tok + (size_t)idxs[row] * K1;
  unsigned short* dst = xb + (size_t)row * K1;
  const int o = threadIdx.x * 8;
  const float4 f0 = *reinterpret_cast<const float4*>(src + o);
  const float4 f1 = *reinterpret_cast<const float4*>(src + o + 4);
  ushortx8 u;
  u[0] = f2bf(f0.x); u[1] = f2bf(f0.y); u[2] = f2bf(f0.z); u[3] = f2bf(f0.w);
  u[4] = f2bf(f1.x); u[5] = f2bf(f1.y); u[6] = f2bf(f1.z); u[7] = f2bf(f1.w);
  *reinterpret_cast<ushortx8*>(dst + o) = u;
}

// 256x256-tile GEMM, BK=64, 8 waves, counted-vmcnt double buffer.
// Coalesced staging: lane l covers chunk (l&7) of row (l>>3) -> 8x128B/wave.
// LDS tile [256 rows][64 shorts] with st_16x32 XOR swizzle (slot ^= row&7),
// applied via inverse-swizzled GLOBAL source + swizzled ds_read (rule #21).
template <int KDIM, int EPI>
__global__ __launch_bounds__(512, 2) void gemm256_kernel(
    const unsigned short* __restrict__ A, const unsigned short* __restrict__ Bw,
    const float* __restrict__ bias, void* __restrict__ outp) {
  __shared__ unsigned short Asub[2][16384];
  __shared__ unsigned short Bsub[2][16384];
  const int t = threadIdx.x;
  const int p = blockIdx.x;
  const int bid = (p & 7) * 32 + (p >> 3);  // XCD x owns contiguous bm range
  const int bm = bid >> 2, bn = bid & 3;
  const int brow0 = bm * 256, bcol0 = bn * 256;
  const int lane = t & 63, w = t >> 6;
  const int wm = w >> 2, wn = w & 3;  // wave grid 2M x 4N, per-wave C 128x64
  const int fr = lane & 15, kg2 = lane >> 4;

  // staging source: row r = (t>>3)+64q, global chunk cg = (t&7) ^ (r&7)
  const int srow = t >> 3;
  const int cg = (t & 7) ^ (srow & 7);
  const unsigned short* aq[4];
  const unsigned short* bq[4];
#pragma unroll
  for (int q = 0; q < 4; ++q) {
    aq[q] = A + (size_t)(brow0 + srow + 64 * q) * KDIM + cg * 8;
    bq[q] = Bw + (size_t)(bcol0 + srow + 64 * q) * KDIM + cg * 8;
  }
  const int t8 = t * 8;  // LDS dest (shorts): row*64 + (t&7)*8 == t*8

  // fragment read bases (shorts): row r at r*64, slot s holds chunk s^(r&7)
  const int arow_sh = (wm * 128 + fr) * 64;
  const int brow_sh = (wn * 64 + fr) * 64;

  floatx4 acc[8][4] = {};
  constexpr int NT = KDIM / 64;

  auto stage = [&](int d, int k0) {
#pragma unroll
    for (int q = 0; q < 4; ++q) {
      gload_lds16(aq[q] + k0, &Asub[d][t8 + q * 4096]);
      gload_lds16(bq[q] + k0, &Bsub[d][t8 + q * 4096]);
    }
  };
  auto compute = [&](int cur) {
#pragma unroll
    for (int ks = 0; ks < 2; ++ks) {
      const int sl = ((ks * 4 + kg2) ^ (fr & 7)) * 8;  // swizzled 16B slot
      short8 bf[4];
#pragma unroll
      for (int j = 0; j < 4; ++j)
        bf[j] = *reinterpret_cast<const short8*>(&Bsub[cur][brow_sh + j * 1024 + sl]);
#pragma unroll
      for (int i = 0; i < 8; ++i) {
        const short8 af = *reinterpret_cast<const short8*>(&Asub[cur][arow_sh + i * 1024 + sl]);
#pragma unroll
        for (int j = 0; j < 4; ++j)
          acc[i][j] = __builtin_amdgcn_mfma_f32_16x16x32_bf16(af, bf[j], acc[i][j], 0, 0, 0);
      }
    }
  };

  stage(0, 0);
#pragma unroll 1
  for (int it = 0; it < NT - 1; ++it) {
    const int cur = it & 1;
    stage(cur ^ 1, (it + 1) * 64);
    // my 8 loads for tile `cur` landed; the 8 just-issued stay in flight
    // across the barrier and the whole MFMA phase.
    asm volatile("s_waitcnt vmcnt(8)\ns_barrier" ::: "memory");
    compute(cur);
    // all my LDS reads done -> after barrier everyone may overwrite this buf
    asm volatile("s_waitcnt lgkmcnt(0)\ns_barrier" ::: "memory");
  }
  asm volatile("s_waitcnt vmcnt(0)\ns_barrier" ::: "memory");
  compute((NT - 1) & 1);

  // epilogue: C/D map col=lane&15, row=(lane>>4)*4+r
  const int er0 = brow0 + wm * 128 + kg2 * 4;
  const int ec0 = bcol0 + wn * 64 + fr;
  if constexpr (EPI == 0) {
    unsigned short* hout = (unsigned short*)outp;
#pragma unroll
    for (int j = 0; j < 4; ++j) {
      const float bv = bias[ec0 + j * 16];
#pragma unroll
      for (int i = 0; i < 8; ++i)
#pragma unroll
        for (int r = 0; r < 4; ++r) {
          float v = acc[i][j][r] + bv;
          v = 0.5f * v * (1.0f + erff(v * 0.70710678118654752f));
          hout[(size_t)(er0 + i * 16 + r) * N1 + (ec0 + j * 16)] = f2bf(v);
        }
    }
  } else {
    float* fout = (float*)outp;
#pragma unroll
    for (int j = 0; j < 4; ++j) {
      const float bv = bias[ec0 + j * 16];
#pragma unroll
      for (int i = 0; i < 8; ++i)
#pragma unroll
        for (int r = 0; r < 4; ++r)
          fout[(size_t)(er0 + i * 16 + r) * N1 + (ec0 + j * 16)] = acc[i][j][r] + bv;
    }
  }
}

extern "C" void kernel_launch(void* const* d_in, const int* in_sizes, int n_in,
                              void* d_out, int out_size, void* d_ws, size_t ws_size,
                              hipStream_t stream) {
  const int* idxs = (const int*)d_in[0];
  const float* tok = (const float*)d_in[1];
  const float* W1 = (const float*)d_in[2];
  const float* b1 = (const float*)d_in[3];
  const float* W2 = (const float*)d_in[4];
  const float* b2 = (const float*)d_in[5];
  float* out = (float*)d_out;

  unsigned short* W1b = (unsigned short*)d_ws;                          // 4 MB
  unsigned short* W2b = (unsigned short*)((char*)d_ws + (4u << 20));    // 2 MB
  unsigned short* xb = (unsigned short*)((char*)d_ws + (6u << 20));     // 64 MB
  unsigned short* hbuf = (unsigned short*)((char*)d_ws + (70u << 20));  // 32 MB

  cvt_bf16_kernel<<<2048, 256, 0, stream>>>(W1, W1b, 524288);
  cvt_bf16_kernel<<<1024, 256, 0, stream>>>(W2, W2b, 262144);
  gather_cvt_kernel<<<16384, 256, 0, stream>>>(idxs, tok, xb);
  gemm256_kernel<2048, 0><<<256, 512, 0, stream>>>(xb, W1b, b1, hbuf);
  gemm256_kernel<1024, 1><<<256, 512, 0, stream>>>(hbuf, W2b, b2, out);
}